// Round 1
// baseline (513.438 us; speedup 1.0000x reference)
//
#include <hip/hip_runtime.h>
#include <cstdint>

// SREChead: stem 1x1 (128->64) + 2x 3x3 (64->64), each BN+SiLU, then 1x1
// reg(4)/obj(1) heads + YOLOX decode. B=64, 80x80, stride 32.
// Strategy: bf16 MFMA (16x16x32) implicit GEMM, NHWC bf16 intermediates in ws.

typedef short short8 __attribute__((ext_vector_type(8)));
typedef float floatx4 __attribute__((ext_vector_type(4)));

#define NPIX 6400
#define NBATCH 64

static __device__ __forceinline__ unsigned short f2bf(float f) {
    unsigned u = __builtin_bit_cast(unsigned, f);
    u += 0x7fffu + ((u >> 16) & 1u);      // round-to-nearest-even
    return (unsigned short)(u >> 16);
}

static __device__ __forceinline__ float silu_(float v) {
    return v / (1.0f + __expf(-v));
}

// ---------------------------------------------------------------------------
// Rearrange 3x3 weights [64co][64ci][3][3] fp32 -> bf16 MFMA B-frag order:
// wB[kb(18)][nt(4)][lane(64)][j(8)], co = nt*16+(lane&15),
// k = kb*32+(lane>>4)*8+j, ci = k&63, tap = k>>6 (= dy*3+dx).
__global__ __launch_bounds__(256) void rearr_w_kernel(
    const float* __restrict__ w1, const float* __restrict__ w2,
    unsigned short* __restrict__ wB1, unsigned short* __restrict__ wB2) {
    int idx = blockIdx.x * 256 + threadIdx.x;          // 0..73727
    const float* src = (idx < 36864) ? w1 : w2;
    unsigned short* dst = (idx < 36864) ? wB1 : wB2;
    int e = (idx < 36864) ? idx : idx - 36864;
    int j = e & 7;
    int lane = (e >> 3) & 63;
    int nt = (e >> 9) & 3;
    int kb = e >> 11;
    int co = nt * 16 + (lane & 15);
    int k = kb * 32 + ((lane >> 4) * 8) + j;
    int ci = k & 63;
    int tap = k >> 6;
    dst[e] = f2bf(src[(co * 64 + ci) * 9 + tap]);
}

// ---------------------------------------------------------------------------
// Stem: f1[b][p][co] = silu(bn(sum_ci x[b][ci][p] * W[co][ci]))  (NHWC bf16 out)
// GEMM M=pixels N=64co K=128ci. Wave: 64 pix x 64 co. Block: 4 waves = 256 pix.
__global__ __launch_bounds__(256) void stem_kernel(
    const float* __restrict__ x, const float* __restrict__ w,
    const float* __restrict__ scale, const float* __restrict__ shift,
    unsigned short* __restrict__ f1) {
    int b = blockIdx.y;
    int wv = threadIdx.x >> 6;
    int lane = threadIdx.x & 63;
    int l15 = lane & 15, q = lane >> 4;
    int pbase = blockIdx.x * 256 + wv * 64;

    // weight (B) fragments, register resident: B[k=ci][n=co] = w[co][ci]
    short8 wf[4][4];
    #pragma unroll
    for (int nt = 0; nt < 4; ++nt) {
        int co = nt * 16 + l15;
        #pragma unroll
        for (int kb = 0; kb < 4; ++kb) {
            const float* wp = w + co * 128 + kb * 32 + q * 8;
            short8 f;
            #pragma unroll
            for (int j = 0; j < 8; ++j) f[j] = (short)f2bf(wp[j]);
            wf[nt][kb] = f;
        }
    }
    float sc[4], sh[4];
    #pragma unroll
    for (int nt = 0; nt < 4; ++nt) {
        sc[nt] = scale[nt * 16 + l15];
        sh[nt] = shift[nt * 16 + l15];
    }

    floatx4 acc[4][4];
    floatx4 zf = {0.0f, 0.0f, 0.0f, 0.0f};
    #pragma unroll
    for (int mt = 0; mt < 4; ++mt)
        #pragma unroll
        for (int nt = 0; nt < 4; ++nt) acc[mt][nt] = zf;

    #pragma unroll
    for (int kb = 0; kb < 4; ++kb) {
        short8 af[4];
        #pragma unroll
        for (int mt = 0; mt < 4; ++mt) {
            int p = pbase + mt * 16 + l15;
            const float* xp = x + (b * 128 + kb * 32 + q * 8) * NPIX + p;
            short8 f;
            #pragma unroll
            for (int j = 0; j < 8; ++j) f[j] = (short)f2bf(xp[j * NPIX]);
            af[mt] = f;
        }
        #pragma unroll
        for (int mt = 0; mt < 4; ++mt)
            #pragma unroll
            for (int nt = 0; nt < 4; ++nt)
                acc[mt][nt] = __builtin_amdgcn_mfma_f32_16x16x32_bf16(
                    af[mt], wf[nt][kb], acc[mt][nt], 0, 0, 0);
    }

    // epilogue: BN + SiLU -> bf16 NHWC
    #pragma unroll
    for (int mt = 0; mt < 4; ++mt) {
        #pragma unroll
        for (int nt = 0; nt < 4; ++nt) {
            int co = nt * 16 + l15;
            #pragma unroll
            for (int r = 0; r < 4; ++r) {
                int p = pbase + mt * 16 + q * 4 + r;   // C/D: row = q*4+r
                float v = acc[mt][nt][r] * sc[nt] + sh[nt];
                f1[(b * NPIX + p) * 64 + co] = f2bf(silu_(v));
            }
        }
    }
}

// ---------------------------------------------------------------------------
// 3x3 conv 64->64 implicit GEMM, K = 18 kb of 32 (tap = kb>>1, ci-half = kb&1).
// BN+SiLU epilogue -> NHWC bf16.
__global__ __launch_bounds__(256) void conv3_kernel(
    const unsigned short* __restrict__ fin, const unsigned short* __restrict__ wB,
    const float* __restrict__ scale, const float* __restrict__ shift,
    unsigned short* __restrict__ fout) {
    int b = blockIdx.y;
    int wv = threadIdx.x >> 6;
    int lane = threadIdx.x & 63;
    int l15 = lane & 15, q = lane >> 4;
    int pbase = blockIdx.x * 256 + wv * 64;

    int py[4], pxl[4];
    #pragma unroll
    for (int mt = 0; mt < 4; ++mt) {
        int pt = pbase + mt * 16;          // 80%16==0 -> tile within one row
        py[mt] = pt / 80;
        pxl[mt] = pt % 80 + l15;
    }

    floatx4 acc[4][4];
    floatx4 zf = {0.0f, 0.0f, 0.0f, 0.0f};
    #pragma unroll
    for (int mt = 0; mt < 4; ++mt)
        #pragma unroll
        for (int nt = 0; nt < 4; ++nt) acc[mt][nt] = zf;

    const unsigned short* fb = fin + b * (NPIX * 64);

    for (int kb = 0; kb < 18; ++kb) {
        int tap = kb >> 1;
        int dy = tap / 3 - 1, dx = tap % 3 - 1;
        int ci0 = (kb & 1) * 32 + q * 8;
        short8 af[4];
        #pragma unroll
        for (int mt = 0; mt < 4; ++mt) {
            int yy = py[mt] + dy, xx = pxl[mt] + dx;
            short8 v = {};
            if ((unsigned)yy < 80u && (unsigned)xx < 80u)
                v = *(const short8*)(fb + (yy * 80 + xx) * 64 + ci0);
            af[mt] = v;
        }
        short8 bfr[4];
        #pragma unroll
        for (int nt = 0; nt < 4; ++nt)
            bfr[nt] = *(const short8*)(wB + ((kb * 4 + nt) * 64 + lane) * 8);
        #pragma unroll
        for (int mt = 0; mt < 4; ++mt)
            #pragma unroll
            for (int nt = 0; nt < 4; ++nt)
                acc[mt][nt] = __builtin_amdgcn_mfma_f32_16x16x32_bf16(
                    af[mt], bfr[nt], acc[mt][nt], 0, 0, 0);
    }

    float sc[4], sh[4];
    #pragma unroll
    for (int nt = 0; nt < 4; ++nt) {
        sc[nt] = scale[nt * 16 + l15];
        sh[nt] = shift[nt * 16 + l15];
    }
    #pragma unroll
    for (int mt = 0; mt < 4; ++mt) {
        #pragma unroll
        for (int nt = 0; nt < 4; ++nt) {
            int co = nt * 16 + l15;
            #pragma unroll
            for (int r = 0; r < 4; ++r) {
                int p = pbase + mt * 16 + q * 4 + r;
                float v = acc[mt][nt][r] * sc[nt] + sh[nt];
                fout[(b * NPIX + p) * 64 + co] = f2bf(silu_(v));
            }
        }
    }
}

// ---------------------------------------------------------------------------
// c2 conv + BN/SiLU + 1x1 heads (reg 4ch, obj 1ch) + YOLOX decode -> out fp32
__global__ __launch_bounds__(256) void conv_head_kernel(
    const unsigned short* __restrict__ fin, const unsigned short* __restrict__ wB,
    const float* __restrict__ scale, const float* __restrict__ shift,
    const float* __restrict__ reg_w, const float* __restrict__ reg_b,
    const float* __restrict__ obj_w, const float* __restrict__ obj_b,
    float* __restrict__ out) {
    __shared__ unsigned short h_lds[4][64 * 72];   // per-wave 64pix x 64co, pad->72
    int b = blockIdx.y;
    int wv = threadIdx.x >> 6;
    int lane = threadIdx.x & 63;
    int l15 = lane & 15, q = lane >> 4;
    int pbase = blockIdx.x * 256 + wv * 64;

    int py[4], pxb[4];
    #pragma unroll
    for (int mt = 0; mt < 4; ++mt) {
        int pt = pbase + mt * 16;
        py[mt] = pt / 80;
        pxb[mt] = pt % 80;
    }

    floatx4 acc[4][4];
    floatx4 zf = {0.0f, 0.0f, 0.0f, 0.0f};
    #pragma unroll
    for (int mt = 0; mt < 4; ++mt)
        #pragma unroll
        for (int nt = 0; nt < 4; ++nt) acc[mt][nt] = zf;

    const unsigned short* fb = fin + b * (NPIX * 64);

    for (int kb = 0; kb < 18; ++kb) {
        int tap = kb >> 1;
        int dy = tap / 3 - 1, dx = tap % 3 - 1;
        int ci0 = (kb & 1) * 32 + q * 8;
        short8 af[4];
        #pragma unroll
        for (int mt = 0; mt < 4; ++mt) {
            int yy = py[mt] + dy, xx = pxb[mt] + l15 + dx;
            short8 v = {};
            if ((unsigned)yy < 80u && (unsigned)xx < 80u)
                v = *(const short8*)(fb + (yy * 80 + xx) * 64 + ci0);
            af[mt] = v;
        }
        short8 bfr[4];
        #pragma unroll
        for (int nt = 0; nt < 4; ++nt)
            bfr[nt] = *(const short8*)(wB + ((kb * 4 + nt) * 64 + lane) * 8);
        #pragma unroll
        for (int mt = 0; mt < 4; ++mt)
            #pragma unroll
            for (int nt = 0; nt < 4; ++nt)
                acc[mt][nt] = __builtin_amdgcn_mfma_f32_16x16x32_bf16(
                    af[mt], bfr[nt], acc[mt][nt], 0, 0, 0);
    }

    // BN + SiLU -> wave-private LDS tile h[p_loc][co] (stride 72 for bank-safety)
    float sc[4], sh[4];
    #pragma unroll
    for (int nt = 0; nt < 4; ++nt) {
        sc[nt] = scale[nt * 16 + l15];
        sh[nt] = shift[nt * 16 + l15];
    }
    unsigned short* hp = h_lds[wv];
    #pragma unroll
    for (int mt = 0; mt < 4; ++mt) {
        #pragma unroll
        for (int nt = 0; nt < 4; ++nt) {
            int co = nt * 16 + l15;
            #pragma unroll
            for (int r = 0; r < 4; ++r) {
                int p_loc = mt * 16 + q * 4 + r;
                float v = acc[mt][nt][r] * sc[nt] + sh[nt];
                hp[p_loc * 72 + co] = f2bf(silu_(v));
            }
        }
    }
    __syncthreads();

    // head B-frags: B[k=co][n] = reg_w[n][co] (n<4), obj_w[co] (n==4), else 0
    short8 hbf[2];
    #pragma unroll
    for (int kb2 = 0; kb2 < 2; ++kb2) {
        int k0 = kb2 * 32 + q * 8;
        short8 f = {};
        if (l15 < 4) {
            #pragma unroll
            for (int j = 0; j < 8; ++j) f[j] = (short)f2bf(reg_w[l15 * 64 + k0 + j]);
        } else if (l15 == 4) {
            #pragma unroll
            for (int j = 0; j < 8; ++j) f[j] = (short)f2bf(obj_w[k0 + j]);
        }
        hbf[kb2] = f;
    }

    floatx4 acc5[4];
    #pragma unroll
    for (int mt = 0; mt < 4; ++mt) acc5[mt] = zf;
    #pragma unroll
    for (int mt = 0; mt < 4; ++mt)
        #pragma unroll
        for (int kb2 = 0; kb2 < 2; ++kb2) {
            short8 a = *(const short8*)(hp + (mt * 16 + l15) * 72 + kb2 * 32 + q * 8);
            acc5[mt] = __builtin_amdgcn_mfma_f32_16x16x32_bf16(a, hbf[kb2], acc5[mt], 0, 0, 0);
        }

    float bias = 0.0f;
    if (l15 < 4) bias = reg_b[l15];
    else if (l15 == 4) bias = obj_b[0];

    #pragma unroll
    for (int mt = 0; mt < 4; ++mt) {
        #pragma unroll
        for (int r = 0; r < 4; ++r) {
            int p = pbase + mt * 16 + q * 4 + r;
            if (l15 < 5) {
                float v = acc5[mt][r] + bias;
                float gx = (float)(pxb[mt] + q * 4 + r);
                float gy = (float)py[mt];
                float o;
                if (l15 == 0)      o = (v + gx) * 32.0f;
                else if (l15 == 1) o = (v + gy) * 32.0f;
                else if (l15 < 4)  o = __expf(v) * 32.0f;
                else               o = 1.0f / (1.0f + __expf(-v));
                out[(b * NPIX + p) * 5 + l15] = o;
            }
        }
    }
}

// ---------------------------------------------------------------------------
extern "C" void kernel_launch(void* const* d_in, const int* in_sizes, int n_in,
                              void* d_out, int out_size, void* d_ws, size_t ws_size,
                              hipStream_t stream) {
    const float* x          = (const float*)d_in[0];
    const float* stem_w     = (const float*)d_in[1];
    const float* stem_scale = (const float*)d_in[2];
    const float* stem_shift = (const float*)d_in[3];
    const float* c1_w       = (const float*)d_in[4];
    const float* c1_scale   = (const float*)d_in[5];
    const float* c1_shift   = (const float*)d_in[6];
    const float* c2_w       = (const float*)d_in[7];
    const float* c2_scale   = (const float*)d_in[8];
    const float* c2_shift   = (const float*)d_in[9];
    const float* reg_w      = (const float*)d_in[10];
    const float* reg_b      = (const float*)d_in[11];
    const float* obj_w      = (const float*)d_in[12];
    const float* obj_b      = (const float*)d_in[13];
    float* out = (float*)d_out;

    // ws layout (ushort units): wB1[36864] | wB2[36864] | f1[64*6400*64] | f2[same]
    const size_t needed = (size_t)(73728 + 2 * 64 * NPIX * 64) * 2;
    if (ws_size < needed) return;  // guard: avoid OOB writes if ws too small

    unsigned short* ws  = (unsigned short*)d_ws;
    unsigned short* wB1 = ws;
    unsigned short* wB2 = ws + 36864;
    unsigned short* f1  = ws + 73728;
    unsigned short* f2  = f1 + 64 * NPIX * 64;

    rearr_w_kernel<<<288, 256, 0, stream>>>(c1_w, c2_w, wB1, wB2);
    stem_kernel<<<dim3(25, 64), 256, 0, stream>>>(x, stem_w, stem_scale, stem_shift, f1);
    conv3_kernel<<<dim3(25, 64), 256, 0, stream>>>(f1, wB1, c1_scale, c1_shift, f2);
    conv_head_kernel<<<dim3(25, 64), 256, 0, stream>>>(f2, wB2, c2_scale, c2_shift,
                                                       reg_w, reg_b, obj_w, obj_b, out);
}